// Round 2
// baseline (2493.467 us; speedup 1.0000x reference)
//
#include <hip/hip_runtime.h>

// Problem: VQ-VAE codebook. z [32,256,32,32] f32, emb [8192,256] f32.
// Outputs concatenated in d_out (f32): z_q [8388608], idx [32768] (as float), loss [1].
//
// Scratch layout inside d_out's z_q region (consumed before k_out overwrites it):
//   [0 .. 2097152)        embT  (256 x 8192)   transposed codebook
//   [2097152 .. 2105344)  se    (8192)         ||e_k||^2
//   [2105344 .. 2138112)  sz    (32768)        ||z_n||^2
#define ZQ_OFF   0
#define EMBT_OFF 0
#define SE_OFF   2097152
#define SZ_OFF   2105344
#define IDX_OFF  8388608
#define LOSS_OFF 8421376

// ---- transpose emb -> embT[d][k] (coalesced writes, scattered reads; 8 MB, tiny)
__global__ void k_prep_transpose(const float* __restrict__ emb, float* __restrict__ embT) {
    int u = blockIdx.x * 256 + threadIdx.x;      // 0 .. 2M, grid = 8192 blocks
    int d = u >> 13;
    int k = u & 8191;
    embT[u] = emb[(size_t)k * 256 + d];
}

// ---- se[k] = sum(emb[k]^2)  (order-insensitive; wave per code, butterfly reduce)
__global__ void k_se(const float* __restrict__ emb, float* __restrict__ se) {
    int w    = (blockIdx.x * 256 + threadIdx.x) >> 6;   // code id
    int lane = threadIdx.x & 63;
    float4 v = *(const float4*)(emb + (size_t)w * 256 + lane * 4);
    float s = v.x * v.x + v.y * v.y + v.z * v.z + v.w * v.w;
    #pragma unroll
    for (int off = 1; off < 64; off <<= 1) s += __shfl_xor(s, off);
    if (lane == 0) se[w] = s;
}

// ---- sz[n] = sum over c of z[b][c][hw]^2 (order-insensitive: same-binade shift invariance)
__global__ void k_sz(const float* __restrict__ z, float* __restrict__ sz) {
    int n  = blockIdx.x * 256 + threadIdx.x;  // grid = 128 blocks
    int b  = n >> 10, hw = n & 1023;
    const float* zp = z + (size_t)b * 262144 + hw;
    float acc = 0.f;
    #pragma unroll 8
    for (int c = 0; c < 256; ++c) { float v = zp[(size_t)c << 10]; acc += v * v; }
    sz[n] = acc;
}

// ---- main: exact-f32-replica distance + argmin
// 512 threads = 8 waves; block covers 32 rows. Wave q owns codes q*1024..q*1024+1023
// (codebook read ONCE per block, not once per wave -> 4x less L1/L2 traffic).
// Lane (jr=j>>3, jc=j&7): thread covers rows {jr, jr+8, jr+16, jr+24} x 4 codes.
// d_nk = fl( fl(sz_n + se_k) - 2*m_nk ),  m = sequential fmaf chain over d=0..255 (BLAS order)
__global__ __launch_bounds__(512, 4) void k_main(
    const float* __restrict__ z, const float* __restrict__ embT,
    const float* __restrict__ se, const float* __restrict__ sz,
    float* __restrict__ idxf, float* __restrict__ lossslot) {
    __shared__ float zt[32][260];     // pad: row stride 260 floats (16B-aligned, banks 4*row)
    __shared__ float szs[32];
    __shared__ float cwd[8][32];
    __shared__ int   cwk[8][32];
    const int tid = threadIdx.x;
    const int blk = blockIdx.x;            // grid = 1024
    const int n0  = blk * 32;
    const int b   = n0 >> 10, hw0 = n0 & 1023;

    // stage z tile (NCHW gather -> LDS [row][c]); coalesced global reads over rows
    {
        const int n  = tid & 31;
        const int cg = tid >> 5;                        // 0..15
        const float* zp = z + (size_t)b * 262144 + hw0 + n;
        for (int cc = 0; cc < 256; cc += 16)
            zt[n][cc + cg] = zp[(size_t)(cc + cg) << 10];
        if (tid < 32) szs[tid] = sz[n0 + tid];
    }
    __syncthreads();

    const int q  = tid >> 6;      // wave id -> code eighth q*1024..
    const int j  = tid & 63;
    const int jr = j >> 3;        // row-lane group 0..7 -> rows jr, jr+8, jr+16, jr+24
    const int jc = j & 7;         // code-lane 0..7 -> 4 codes each

    float szr[4];
    #pragma unroll
    for (int rr = 0; rr < 4; ++rr) szr[rr] = szs[rr * 8 + jr];

    float bestd[4]; int bestk[4];
    #pragma unroll
    for (int rr = 0; rr < 4; ++rr) { bestd[rr] = 3.4e38f; bestk[rr] = 0; }

    for (int tile = 0; tile < 32; ++tile) {
        const int c0 = q * 1024 + tile * 32 + jc * 4;
        float acc[4][4];
        #pragma unroll
        for (int rr = 0; rr < 4; ++rr)
            #pragma unroll
            for (int c = 0; c < 4; ++c) acc[rr][c] = 0.f;

        for (int t = 0; t < 64; ++t) {                 // d-chunks of 4, ascending
            float4 ef[4];
            #pragma unroll
            for (int dd = 0; dd < 4; ++dd)
                ef[dd] = *(const float4*)(embT + (size_t)(t * 4 + dd) * 8192 + c0);
            float4 zr[4];
            #pragma unroll
            for (int rr = 0; rr < 4; ++rr)
                zr[rr] = *(const float4*)(&zt[rr * 8 + jr][t * 4]);
            #pragma unroll
            for (int dd = 0; dd < 4; ++dd) {
                #pragma unroll
                for (int rr = 0; rr < 4; ++rr) {
                    const float zv = ((const float*)&zr[rr])[dd];
                    #pragma unroll
                    for (int c = 0; c < 4; ++c)
                        acc[rr][c] = fmaf(zv, ((const float*)&ef[dd])[c], acc[rr][c]);
                }
            }
        }
        // epilogue: replicate fl(fl(sz+se) - 2m); ascending c per row; strict < keeps first min
        const float4 se4 = *(const float4*)(se + c0);
        #pragma unroll
        for (int c = 0; c < 4; ++c) {
            const float sek = ((const float*)&se4)[c];
            #pragma unroll
            for (int rr = 0; rr < 4; ++rr) {
                float A  = szr[rr] + sek;
                float dq = A - 2.0f * acc[rr][c];
                if (dq < bestd[rr]) { bestd[rr] = dq; bestk[rr] = c0 + c; }
            }
        }
    }
    // reduce across the 8 jc-lanes (same jr share rows); tie-break lowest k
    #pragma unroll
    for (int rr = 0; rr < 4; ++rr) {
        float d = bestd[rr]; int k = bestk[rr];
        #pragma unroll
        for (int off = 1; off < 8; off <<= 1) {
            float od = __shfl_xor(d, off);
            int   ok = __shfl_xor(k, off);
            if (od < d || (od == d && ok < k)) { d = od; k = ok; }
        }
        if (jc == 0) { cwd[q][rr * 8 + jr] = d; cwk[q][rr * 8 + jr] = k; }
    }
    __syncthreads();
    // combine the 8 wave-partials per row; ascending q = ascending code ranges,
    // strict < keeps the earliest (lowest-k) minimum
    if (tid < 32) {
        float d = cwd[0][tid]; int k = cwk[0][tid];
        #pragma unroll
        for (int w = 1; w < 8; ++w) {
            float od = cwd[w][tid];
            if (od < d) { d = od; k = cwk[w][tid]; }
        }
        idxf[n0 + tid] = (float)k;
    }
    if (blk == 0 && tid == 0) *lossslot = 0.f;   // init loss accumulator (runs before k_out)
}

// ---- z_q (STE-exact) + loss partial sums
__global__ void k_out(const float* __restrict__ z, const float* __restrict__ emb,
                      const float* __restrict__ idxf, float* __restrict__ zq,
                      float* __restrict__ lossslot) {
    int u   = blockIdx.x * 256 + threadIdx.x;   // grid = 8192 blocks (2M threads)
    int cc4 = u >> 15;                          // 0..63 (uniform per block)
    int n   = u & 32767;
    int b   = n >> 10, hw = n & 1023;
    int k   = (int)idxf[n];
    const float4 q4 = *(const float4*)(emb + (size_t)k * 256 + cc4 * 4);
    float ls = 0.f;
    #pragma unroll
    for (int c = 0; c < 4; ++c) {
        size_t zi = (size_t)b * 262144 + (size_t)(cc4 * 4 + c) * 1024 + hw;
        float zv   = z[zi];
        float qv   = ((const float*)&q4)[c];
        float diff = qv - zv;        // fl(q - z)
        zq[zi]     = zv + diff;      // fl(z + fl(q - z))  == reference STE output
        ls += diff * diff;
    }
    #pragma unroll
    for (int off = 1; off < 64; off <<= 1) ls += __shfl_xor(ls, off);
    if ((threadIdx.x & 63) == 0) atomicAdd(lossslot, ls);
}

__global__ void k_fin(float* __restrict__ lossslot) {
    float S = *lossslot;
    float m = S / 8388608.0f;        // /2^23 exact scaling
    *lossslot = m + 0.25f * m;       // fl(m1 + fl(beta*m2)), m1==m2
}

extern "C" void kernel_launch(void* const* d_in, const int* in_sizes, int n_in,
                              void* d_out, int out_size, void* d_ws, size_t ws_size,
                              hipStream_t stream) {
    const float* z   = (const float*)d_in[0];
    const float* emb = (const float*)d_in[1];
    float* out  = (float*)d_out;
    float* embT = out + EMBT_OFF;
    float* se   = out + SE_OFF;
    float* sz   = out + SZ_OFF;
    float* idxf = out + IDX_OFF;
    float* loss = out + LOSS_OFF;

    k_prep_transpose<<<8192, 256, 0, stream>>>(emb, embT);
    k_se<<<2048, 256, 0, stream>>>(emb, se);
    k_sz<<<128, 256, 0, stream>>>(z, sz);
    k_main<<<1024, 512, 0, stream>>>(z, embT, se, sz, idxf, loss);
    k_out<<<8192, 256, 0, stream>>>(z, emb, idxf, out + ZQ_OFF, loss);
    k_fin<<<1, 1, 0, stream>>>(loss);
}

// Round 3
// 2443.192 us; speedup vs baseline: 1.0206x; 1.0206x over previous
//
#include <hip/hip_runtime.h>

// Problem: VQ-VAE codebook. z [32,256,32,32] f32, emb [8192,256] f32.
// Outputs concatenated in d_out (f32): z_q [8388608], idx [32768] (as float), loss [1].
//
// Scratch layout inside d_out's z_q region (consumed before k_out overwrites it):
//   [0 .. 2097152)        embT  (256 x 8192)   transposed codebook
//   [2097152 .. 2105344)  se    (8192)         ||e_k||^2
//   [2105344 .. 2138112)  sz    (32768)        ||z_n||^2
#define ZQ_OFF   0
#define EMBT_OFF 0
#define SE_OFF   2097152
#define SZ_OFF   2105344
#define IDX_OFF  8388608
#define LOSS_OFF 8421376

// ---- transpose emb -> embT[d][k] (coalesced writes, scattered reads; 8 MB, tiny)
__global__ void k_prep_transpose(const float* __restrict__ emb, float* __restrict__ embT) {
    int u = blockIdx.x * 256 + threadIdx.x;      // 0 .. 2M, grid = 8192 blocks
    int d = u >> 13;
    int k = u & 8191;
    embT[u] = emb[(size_t)k * 256 + d];
}

// ---- se[k] = sum(emb[k]^2)  (order-insensitive; wave per code, butterfly reduce)
__global__ void k_se(const float* __restrict__ emb, float* __restrict__ se) {
    int w    = (blockIdx.x * 256 + threadIdx.x) >> 6;   // code id
    int lane = threadIdx.x & 63;
    float4 v = *(const float4*)(emb + (size_t)w * 256 + lane * 4);
    float s = v.x * v.x + v.y * v.y + v.z * v.z + v.w * v.w;
    #pragma unroll
    for (int off = 1; off < 64; off <<= 1) s += __shfl_xor(s, off);
    if (lane == 0) se[w] = s;
}

// ---- sz[n] = sum over c of z[b][c][hw]^2 (order-insensitive: same-binade shift invariance)
__global__ void k_sz(const float* __restrict__ z, float* __restrict__ sz) {
    int n  = blockIdx.x * 256 + threadIdx.x;  // grid = 128 blocks
    int b  = n >> 10, hw = n & 1023;
    const float* zp = z + (size_t)b * 262144 + hw;
    float acc = 0.f;
    #pragma unroll 8
    for (int c = 0; c < 256; ++c) { float v = zp[(size_t)c << 10]; acc += v * v; }
    sz[n] = acc;
}

// ---- main: exact-f32-replica distance + argmin, LDS-staged GEMM structure.
// 256 thr = 4 waves, 32 rows/block, grid 1024. Wave w owns rows w*8..w*8+7 (disjoint).
// Lane j owns codes tile*256 + j*4..+3. embT streamed through LDS in 16d x 256c chunks,
// double-buffered, reg-staged (loads issued a chunk ahead, write after compute).
// d_nk = fl( fl(sz_n + se_k) - 2*m_nk ),  m = sequential fmaf chain over d=0..255 (BLAS order)
__global__ __launch_bounds__(256, 2) void k_main(
    const float* __restrict__ z, const float* __restrict__ embT,
    const float* __restrict__ se, const float* __restrict__ sz,
    float* __restrict__ idxf, float* __restrict__ lossslot) {
    __shared__ float zt[32][256];        // col XOR-swizzled by ((row&7)<<2)
    __shared__ float efb[2][16][256];    // double-buffered ef chunk (16 d x 256 codes)
    const int tid = threadIdx.x;
    const int blk = blockIdx.x;          // grid = 1024
    const int n0  = blk * 32;
    const int b   = n0 >> 10, hw0 = n0 & 1023;

    const int w = tid >> 6;              // wave 0..3 -> rows w*8..w*8+7
    const int j = tid & 63;              // lane -> 4 codes per tile

    // stage z tile (NCHW gather -> LDS [row][c^((row&7)<<2)])
    {
        const int n  = tid & 31;
        const int cg = tid >> 5;                        // 0..7
        const float* zp = z + (size_t)b * 262144 + hw0 + n;
        const int sw = (n & 7) << 2;
        for (int cc = 0; cc < 256; cc += 8) {
            int c = cc + cg;
            zt[n][c ^ sw] = zp[(size_t)c << 10];
        }
    }

    // staging geometry: thread covers 4 rows (i*4 + srow) of the 16-row chunk, 4 floats each
    const int srow = tid >> 6;                          // 0..3
    const int scol = (tid & 63) * 4;

    // prologue: stage chunk 0 (ct=0, dc=0) into efb[0]
    float4 st[4];
    #pragma unroll
    for (int i = 0; i < 4; ++i)
        st[i] = *(const float4*)(embT + (size_t)(i * 4 + srow) * 8192 + scol);
    #pragma unroll
    for (int i = 0; i < 4; ++i)
        *(float4*)&efb[0][i * 4 + srow][scol] = st[i];
    __syncthreads();

    float szr[8];
    #pragma unroll
    for (int rr = 0; rr < 8; ++rr) szr[rr] = sz[n0 + w * 8 + rr];

    float bestd[8]; int bestk[8];
    #pragma unroll
    for (int rr = 0; rr < 8; ++rr) { bestd[rr] = 3.4e38f; bestk[rr] = 0; }

    int buf = 0;
    for (int ct = 0; ct < 32; ++ct) {
        float acc[8][4];
        #pragma unroll
        for (int rr = 0; rr < 8; ++rr)
            #pragma unroll
            for (int c = 0; c < 4; ++c) acc[rr][c] = 0.f;

        for (int dc = 0; dc < 16; ++dc) {
            const int lin = ct * 16 + dc;
            const bool more = (lin + 1) < 512;
            if (more) {
                const int ct2 = (lin + 1) >> 4, dc2 = (lin + 1) & 15;
                const float* g = embT + (size_t)dc2 * 16 * 8192 + ct2 * 256 + scol;
                #pragma unroll
                for (int i = 0; i < 4; ++i)
                    st[i] = *(const float4*)(g + (size_t)(i * 4 + srow) * 8192);
            }
            // compute chunk dc from efb[buf]; d = dc*16 + t*4 + dd ascending
            #pragma unroll
            for (int t = 0; t < 4; ++t) {
                float4 ef4[4];
                #pragma unroll
                for (int dd = 0; dd < 4; ++dd)
                    ef4[dd] = *(const float4*)&efb[buf][t * 4 + dd][j * 4];
                float4 zr[8];
                #pragma unroll
                for (int rr = 0; rr < 8; ++rr)
                    zr[rr] = *(const float4*)&zt[w * 8 + rr][(dc * 16 + t * 4) ^ (rr << 2)];
                #pragma unroll
                for (int dd = 0; dd < 4; ++dd) {
                    #pragma unroll
                    for (int rr = 0; rr < 8; ++rr) {
                        const float zv = ((const float*)&zr[rr])[dd];
                        #pragma unroll
                        for (int c = 0; c < 4; ++c)
                            acc[rr][c] = fmaf(zv, ((const float*)&ef4[dd])[c], acc[rr][c]);
                    }
                }
            }
            if (more) {
                #pragma unroll
                for (int i = 0; i < 4; ++i)
                    *(float4*)&efb[buf ^ 1][i * 4 + srow][scol] = st[i];
            }
            __syncthreads();
            buf ^= 1;
        }
        // epilogue: replicate fl(fl(sz+se) - 2m); ascending c per row; strict < keeps first min
        const int c0 = ct * 256 + j * 4;
        const float4 se4 = *(const float4*)(se + c0);
        #pragma unroll
        for (int c = 0; c < 4; ++c) {
            const float sek = ((const float*)&se4)[c];
            #pragma unroll
            for (int rr = 0; rr < 8; ++rr) {
                float A  = szr[rr] + sek;
                float dq = A - 2.0f * acc[rr][c];
                if (dq < bestd[rr]) { bestd[rr] = dq; bestk[rr] = c0 + c; }
            }
        }
    }
    // reduce across the 64 lanes (codes ascending with j); tie-break lowest k
    #pragma unroll
    for (int rr = 0; rr < 8; ++rr) {
        float d = bestd[rr]; int k = bestk[rr];
        #pragma unroll
        for (int off = 1; off < 64; off <<= 1) {
            float od = __shfl_xor(d, off);
            int   ok = __shfl_xor(k, off);
            if (od < d || (od == d && ok < k)) { d = od; k = ok; }
        }
        if (j == 0) idxf[n0 + w * 8 + rr] = (float)k;
    }
    if (blk == 0 && tid == 0) *lossslot = 0.f;   // init loss accumulator (runs before k_out)
}

// ---- z_q (STE-exact) + loss partial sums
__global__ void k_out(const float* __restrict__ z, const float* __restrict__ emb,
                      const float* __restrict__ idxf, float* __restrict__ zq,
                      float* __restrict__ lossslot) {
    int u   = blockIdx.x * 256 + threadIdx.x;   // grid = 8192 blocks (2M threads)
    int cc4 = u >> 15;                          // 0..63 (uniform per block)
    int n   = u & 32767;
    int b   = n >> 10, hw = n & 1023;
    int k   = (int)idxf[n];
    const float4 q4 = *(const float4*)(emb + (size_t)k * 256 + cc4 * 4);
    float ls = 0.f;
    #pragma unroll
    for (int c = 0; c < 4; ++c) {
        size_t zi = (size_t)b * 262144 + (size_t)(cc4 * 4 + c) * 1024 + hw;
        float zv   = z[zi];
        float qv   = ((const float*)&q4)[c];
        float diff = qv - zv;        // fl(q - z)
        zq[zi]     = zv + diff;      // fl(z + fl(q - z))  == reference STE output
        ls += diff * diff;
    }
    #pragma unroll
    for (int off = 1; off < 64; off <<= 1) ls += __shfl_xor(ls, off);
    if ((threadIdx.x & 63) == 0) atomicAdd(lossslot, ls);
}

__global__ void k_fin(float* __restrict__ lossslot) {
    float S = *lossslot;
    float m = S / 8388608.0f;        // /2^23 exact scaling
    *lossslot = m + 0.25f * m;       // fl(m1 + fl(beta*m2)), m1==m2
}

extern "C" void kernel_launch(void* const* d_in, const int* in_sizes, int n_in,
                              void* d_out, int out_size, void* d_ws, size_t ws_size,
                              hipStream_t stream) {
    const float* z   = (const float*)d_in[0];
    const float* emb = (const float*)d_in[1];
    float* out  = (float*)d_out;
    float* embT = out + EMBT_OFF;
    float* se   = out + SE_OFF;
    float* sz   = out + SZ_OFF;
    float* idxf = out + IDX_OFF;
    float* loss = out + LOSS_OFF;

    k_prep_transpose<<<8192, 256, 0, stream>>>(emb, embT);
    k_se<<<2048, 256, 0, stream>>>(emb, se);
    k_sz<<<128, 256, 0, stream>>>(z, sz);
    k_main<<<1024, 256, 0, stream>>>(z, embT, se, sz, idxf, loss);
    k_out<<<8192, 256, 0, stream>>>(z, emb, idxf, out + ZQ_OFF, loss);
    k_fin<<<1, 1, 0, stream>>>(loss);
}

// Round 4
// 2290.418 us; speedup vs baseline: 1.0887x; 1.0667x over previous
//
#include <hip/hip_runtime.h>

// Problem: VQ-VAE codebook. z [32,256,32,32] f32, emb [8192,256] f32.
// Outputs concatenated in d_out (f32): z_q [8388608], idx [32768] (as float), loss [1].
//
// Scratch layout inside d_out's z_q region (consumed before k_out overwrites it):
//   [0 .. 2097152)        embT  (256 x 8192)   transposed codebook
//   [2097152 .. 2105344)  se    (8192)         ||e_k||^2
//   [2105344 .. 2138112)  sz    (32768)        ||z_n||^2
#define ZQ_OFF   0
#define EMBT_OFF 0
#define SE_OFF   2097152
#define SZ_OFF   2105344
#define IDX_OFF  8388608
#define LOSS_OFF 8421376

// ---- transpose emb -> embT[d][k] (coalesced writes, scattered reads; 8 MB, tiny)
__global__ void k_prep_transpose(const float* __restrict__ emb, float* __restrict__ embT) {
    int u = blockIdx.x * 256 + threadIdx.x;      // 0 .. 2M, grid = 8192 blocks
    int d = u >> 13;
    int k = u & 8191;
    embT[u] = emb[(size_t)k * 256 + d];
}

// ---- se[k] = sum(emb[k]^2)  (order-insensitive; wave per code, butterfly reduce)
__global__ void k_se(const float* __restrict__ emb, float* __restrict__ se) {
    int w    = (blockIdx.x * 256 + threadIdx.x) >> 6;   // code id
    int lane = threadIdx.x & 63;
    float4 v = *(const float4*)(emb + (size_t)w * 256 + lane * 4);
    float s = v.x * v.x + v.y * v.y + v.z * v.z + v.w * v.w;
    #pragma unroll
    for (int off = 1; off < 64; off <<= 1) s += __shfl_xor(s, off);
    if (lane == 0) se[w] = s;
}

// ---- sz[n] = sum over c of z[b][c][hw]^2 (order-insensitive: same-binade shift invariance)
__global__ void k_sz(const float* __restrict__ z, float* __restrict__ sz) {
    int n  = blockIdx.x * 256 + threadIdx.x;  // grid = 128 blocks
    int b  = n >> 10, hw = n & 1023;
    const float* zp = z + (size_t)b * 262144 + hw;
    float acc = 0.f;
    #pragma unroll 8
    for (int c = 0; c < 256; ++c) { float v = zp[(size_t)c << 10]; acc += v * v; }
    sz[n] = acc;
}

// ---- main: exact-f32-replica distance + argmin.
// 256 thr = 4 waves = (2 row-groups x 2 code-groups); 32 rows/block; grid 1024 (=4 blk/CU).
// Per thread: R=16 rows x C=4 codes (acc 64 VGPR). z-tile transposed in LDS (ztT[d][row])
// so z reads are 4 broadcast ds_read_b128 per d; ef read from global (L2/L3-resident embT,
// 0.25 B/FMA lane traffic) with one-d register prefetch. Argmin state lives in LDS,
// updated per 512-code tile with full (d,k) tie-break (lowest k on equality).
// d_nk = fl( fl(sz_n + se_k) - 2*m_nk ),  m = sequential fmaf chain over d=0..255 (BLAS order)
__global__ __launch_bounds__(256, 4) void k_main(
    const float* __restrict__ z, const float* __restrict__ embT,
    const float* __restrict__ se, const float* __restrict__ sz,
    float* __restrict__ idxf, float* __restrict__ lossslot) {
    __shared__ float ztT[256][32];        // [d][row], row-major 128B rows
    __shared__ float szs[32];
    __shared__ float cwd[2][2][16];       // [codegrp][rowgrp][row] best distance
    __shared__ int   cwk[2][2][16];       // matching code id
    const int tid = threadIdx.x;
    const int blk = blockIdx.x;           // grid = 1024
    const int n0  = blk * 32;
    const int b   = n0 >> 10, hw0 = n0 & 1023;

    // stage z tile transposed: ztT[c][n]; coalesced global reads over n
    {
        const int n  = tid & 31;
        const int cg = tid >> 5;                        // 0..7
        const float* zp = z + (size_t)b * 262144 + hw0 + n;
        #pragma unroll
        for (int cc = 0; cc < 256; cc += 8)
            ztT[cc + cg][n] = zp[(size_t)(cc + cg) << 10];
        if (tid < 32) szs[tid] = sz[n0 + tid];
        if (tid < 64) { (&cwd[0][0][0])[tid] = 3.4e38f; (&cwk[0][0][0])[tid] = 0; }
    }
    __syncthreads();

    const int w   = tid >> 6;     // wave 0..3
    const int rg  = w & 1;        // row group: rows rg*16 .. rg*16+15
    const int cgr = w >> 1;       // code group within each 512-code tile
    const int j   = tid & 63;     // lane -> 4 codes
    const int r0  = rg * 16;

    for (int tile = 0; tile < 16; ++tile) {
        const int c0 = tile * 512 + cgr * 256 + j * 4;
        const float* ep = embT + c0;
        float acc[16][4];
        #pragma unroll
        for (int rr = 0; rr < 16; ++rr)
            #pragma unroll
            for (int c = 0; c < 4; ++c) acc[rr][c] = 0.f;

        float4 efn = *(const float4*)ep;               // prefetch d=0
        #pragma unroll 4
        for (int d = 0; d < 256; ++d) {
            const float4 efc = efn;
            // prefetch d+1 (wraps to d=0 at the end; harmless extra load)
            efn = *(const float4*)(ep + (size_t)((d + 1) & 255) * 8192);
            float4 zv[4];
            #pragma unroll
            for (int i = 0; i < 4; ++i)
                zv[i] = *(const float4*)&ztT[d][r0 + i * 4];
            #pragma unroll
            for (int i = 0; i < 4; ++i) {
                #pragma unroll
                for (int q = 0; q < 4; ++q) {
                    const float zx = ((const float*)&zv[i])[q];
                    const int rr = i * 4 + q;
                    acc[rr][0] = fmaf(zx, efc.x, acc[rr][0]);
                    acc[rr][1] = fmaf(zx, efc.y, acc[rr][1]);
                    acc[rr][2] = fmaf(zx, efc.z, acc[rr][2]);
                    acc[rr][3] = fmaf(zx, efc.w, acc[rr][3]);
                }
            }
        }

        // epilogue: dq = fl( fl(sz+se) - 2m ); per-row argmin over this tile's 256 codes
        const float4 se4 = *(const float4*)(se + c0);
        #pragma unroll
        for (int rr = 0; rr < 16; ++rr) {
            const float szv = szs[r0 + rr];
            float bd = 3.4e38f; int bk = 0;
            #pragma unroll
            for (int c = 0; c < 4; ++c) {               // ascending c; strict < keeps first
                float A  = szv + ((const float*)&se4)[c];
                float dq = A - 2.0f * acc[rr][c];
                if (dq < bd) { bd = dq; bk = c0 + c; }
            }
            #pragma unroll
            for (int off = 1; off < 64; off <<= 1) {    // full tie-break: lowest k
                float od = __shfl_xor(bd, off);
                int   ok = __shfl_xor(bk, off);
                if (od < bd || (od == bd && ok < bk)) { bd = od; bk = ok; }
            }
            if (j == 0) {
                float pd = cwd[cgr][rg][rr]; int pk = cwk[cgr][rg][rr];
                if (bd < pd || (bd == pd && bk < pk)) {
                    cwd[cgr][rg][rr] = bd; cwk[cgr][rg][rr] = bk;
                }
            }
        }
    }
    __syncthreads();
    // merge the 2 code-groups per row with full tie-break (code ranges interleave)
    if (tid < 32) {
        const int rgx = tid >> 4, row = tid & 15;
        float d0 = cwd[0][rgx][row]; int k0 = cwk[0][rgx][row];
        float d1 = cwd[1][rgx][row]; int k1 = cwk[1][rgx][row];
        if (d1 < d0 || (d1 == d0 && k1 < k0)) { d0 = d1; k0 = k1; }
        idxf[n0 + rgx * 16 + row] = (float)k0;
    }
    if (blk == 0 && tid == 0) *lossslot = 0.f;   // init loss accumulator (runs before k_out)
}

// ---- z_q (STE-exact) + loss partial sums
__global__ void k_out(const float* __restrict__ z, const float* __restrict__ emb,
                      const float* __restrict__ idxf, float* __restrict__ zq,
                      float* __restrict__ lossslot) {
    int u   = blockIdx.x * 256 + threadIdx.x;   // grid = 8192 blocks (2M threads)
    int cc4 = u >> 15;                          // 0..63 (uniform per block)
    int n   = u & 32767;
    int b   = n >> 10, hw = n & 1023;
    int k   = (int)idxf[n];
    const float4 q4 = *(const float4*)(emb + (size_t)k * 256 + cc4 * 4);
    float ls = 0.f;
    #pragma unroll
    for (int c = 0; c < 4; ++c) {
        size_t zi = (size_t)b * 262144 + (size_t)(cc4 * 4 + c) * 1024 + hw;
        float zv   = z[zi];
        float qv   = ((const float*)&q4)[c];
        float diff = qv - zv;        // fl(q - z)
        zq[zi]     = zv + diff;      // fl(z + fl(q - z))  == reference STE output
        ls += diff * diff;
    }
    #pragma unroll
    for (int off = 1; off < 64; off <<= 1) ls += __shfl_xor(ls, off);
    if ((threadIdx.x & 63) == 0) atomicAdd(lossslot, ls);
}

__global__ void k_fin(float* __restrict__ lossslot) {
    float S = *lossslot;
    float m = S / 8388608.0f;        // /2^23 exact scaling
    *lossslot = m + 0.25f * m;       // fl(m1 + fl(beta*m2)), m1==m2
}

extern "C" void kernel_launch(void* const* d_in, const int* in_sizes, int n_in,
                              void* d_out, int out_size, void* d_ws, size_t ws_size,
                              hipStream_t stream) {
    const float* z   = (const float*)d_in[0];
    const float* emb = (const float*)d_in[1];
    float* out  = (float*)d_out;
    float* embT = out + EMBT_OFF;
    float* se   = out + SE_OFF;
    float* sz   = out + SZ_OFF;
    float* idxf = out + IDX_OFF;
    float* loss = out + LOSS_OFF;

    k_prep_transpose<<<8192, 256, 0, stream>>>(emb, embT);
    k_se<<<2048, 256, 0, stream>>>(emb, se);
    k_sz<<<128, 256, 0, stream>>>(z, sz);
    k_main<<<1024, 256, 0, stream>>>(z, embT, se, sz, idxf, loss);
    k_out<<<8192, 256, 0, stream>>>(z, emb, idxf, out + ZQ_OFF, loss);
    k_fin<<<1, 1, 0, stream>>>(loss);
}